// Round 12
// baseline (204.413 us; speedup 1.0000x reference)
//
#include <hip/hip_runtime.h>
#include <hip/hip_cooperative_groups.h>
#include <math.h>

namespace cg = cooperative_groups;

#define NT  16384
#define HID 2048
#define NE  8
#define NBLK 512   // router blocks

constexpr int TOP_OFF  = 0;                 // top_scores  (NT,2)
constexpr int SC_OFF   = NT * 2;            // scores      (NT,8)
constexpr int IDX_OFF  = SC_OFF + NT * NE;  // indices     (NT,2)
constexpr int HIST_OFF = IDX_OFF + NT * 2;  // counts      (8)
constexpr int ENT_OFF  = HIST_OFF + NE;     // entropy     (1)

// ws layout: float ws[NBLK][12] — [0..7]=hist, [8]=ent, [9..11]=pad
constexpr int WS_ROW = 12;

typedef float f32x4 __attribute__((ext_vector_type(4)));

// Nontemporal stream load: x is read-once (128 MB) — don't allocate in L2/L3.
static __device__ __forceinline__ f32x4 ntload4(const float* p) {
  return __builtin_nontemporal_load(reinterpret_cast<const f32x4*>(p));
}

__global__ void init_tail(float* __restrict__ out) {
  const int i = threadIdx.x;
  if (i < NE + 1) out[HIST_OFF + i] = 0.0f;
}

// X-macro over experts: NAMED scalars only — no indexable per-thread arrays
// (round 1's arrays spilled ~210 MB of scratch to HBM).
#define FOR_E(F) F(0) F(1) F(2) F(3) F(4) F(5) F(6) F(7)

// ---------------------------------------------------------------------------
// Router body (shared by cooperative and separate-kernel paths).
// 512 threads = 8 waves/block; 64.5 KiB LDS -> 2 blocks/CU -> 16 waves/CU.
// ---------------------------------------------------------------------------
template <bool USE_WS>
__device__ __forceinline__ void router_body(
    const float* __restrict__ x, const float* __restrict__ W,
    const float* __restrict__ bias, float* __restrict__ out,
    float* __restrict__ ws) {
  __shared__ float sW[NE * HID];   // 64 KiB
  __shared__ int   sHist[NE];
  __shared__ float sEnt;

  const int tid  = threadIdx.x;
  const int wave = tid >> 6;
  const int lane = tid & 63;

  // 4 tokens per wave, 32 per block, 512 blocks.
  const int t0 = blockIdx.x * 32 + wave * 4;
  const float* xb = x + (size_t)t0 * HID;
  // Column-phase rotation — ESSENTIAL (round 9 ablation: removing it cost
  // +6 µs; spreads concurrent requests across HBM channels).
  const int phase = (wave + (int)blockIdx.x) & 7;

#define OFFX(it) ((((it) + phase) & 7) * 256 + lane * 4)
#define XLOAD(N, off)                                                      \
  N##0 = ntload4(xb + (off));                                              \
  N##1 = ntload4(xb + HID + (off));                                        \
  N##2 = ntload4(xb + 2 * HID + (off));                                    \
  N##3 = ntload4(xb + 3 * HID + (off));

  f32x4 A0, A1, A2, A3, B0, B1, B2, B3;

  // ---- PEELED iter-0 x loads, issued BEFORE W staging: the x stream starts
  // flowing during the W-staging latency (round 11: −0.75 µs).
  { const int o0 = OFFX(0); XLOAD(A, o0) }

  // Stage W into LDS: 16384 floats = 4096 float4.
#if __has_builtin(__builtin_amdgcn_global_load_lds)
  // Direct global->LDS DMA, 16 B/lane: no VGPR round-trip. LDS dest rule
  // (m104): wave-uniform base + lane*16.
  {
    const float4* Wv  = reinterpret_cast<const float4*>(W);
    float4*       sWv = reinterpret_cast<float4*>(sW);
#pragma unroll
    for (int i = 0; i < 8; ++i) {
      const float4* gsrc = Wv + i * 512 + tid;        // per-lane
      float4*       ldst = sWv + i * 512 + wave * 64; // wave-uniform
      __builtin_amdgcn_global_load_lds(
          (const __attribute__((address_space(1))) void*)gsrc,
          (__attribute__((address_space(3))) void*)ldst, 16, 0, 0);
    }
  }
#else
  {
    const float4* Wv  = reinterpret_cast<const float4*>(W);
    float4*       sWv = reinterpret_cast<float4*>(sW);
#pragma unroll
    for (int i = 0; i < 8; ++i) sWv[i * 512 + tid] = Wv[i * 512 + tid];
  }
#endif
  if (tid < NE) sHist[tid] = 0;
  if (tid == 0) sEnt = 0.0f;

#define DECL_BS(e) const float bs_##e = bias[e];
  FOR_E(DECL_BS)

  __syncthreads();   // drains vmcnt(0): W in LDS and peeled A in VGPRs

#define DECL_ACC(e) float a0_##e = 0.f, a1_##e = 0.f, a2_##e = 0.f, a3_##e = 0.f;
  FOR_E(DECL_ACC)

  // NOTE: C##0.x is an invalid paste ("0.x" lexes as one pp-number), so bind
  // local copies first; compiler copy-propagates them away.
#define FMA_E(e, q0, q1, q2, q3, offc)                                     \
  {                                                                        \
    const float4 wv = *reinterpret_cast<const float4*>(sW + e * HID + (offc)); \
    a0_##e += q0.x * wv.x + q0.y * wv.y + q0.z * wv.z + q0.w * wv.w;       \
    a1_##e += q1.x * wv.x + q1.y * wv.y + q1.z * wv.z + q1.w * wv.w;       \
    a2_##e += q2.x * wv.x + q2.y * wv.y + q2.z * wv.z + q2.w * wv.w;       \
    a3_##e += q3.x * wv.x + q3.y * wv.y + q3.z * wv.z + q3.w * wv.w;       \
  }

#define FMA_ALL(q0, q1, q2, q3, offc)                                      \
    FMA_E(0, q0, q1, q2, q3, offc) FMA_E(1, q0, q1, q2, q3, offc)          \
    FMA_E(2, q0, q1, q2, q3, offc) FMA_E(3, q0, q1, q2, q3, offc)          \
    FMA_E(4, q0, q1, q2, q3, offc) FMA_E(5, q0, q1, q2, q3, offc)          \
    FMA_E(6, q0, q1, q2, q3, offc) FMA_E(7, q0, q1, q2, q3, offc)

#define BODY(C, N, itc)                                                    \
  {                                                                        \
    const int offn = OFFX(itc + 1);                                        \
    XLOAD(N, offn)                                                         \
    const f32x4 q0 = C##0 , q1 = C##1 , q2 = C##2 , q3 = C##3 ;            \
    const int offc = OFFX(itc);                                            \
    FMA_ALL(q0, q1, q2, q3, offc)                                          \
  }
#define BODY_LAST(C, itc)                                                  \
  {                                                                        \
    const f32x4 q0 = C##0 , q1 = C##1 , q2 = C##2 , q3 = C##3 ;            \
    const int offc = OFFX(itc);                                            \
    FMA_ALL(q0, q1, q2, q3, offc)                                          \
  }

  BODY(A, B, 0)
  BODY(B, A, 1)
  BODY(A, B, 2)
  BODY(B, A, 3)
  BODY(A, B, 4)
  BODY(B, A, 5)
  BODY(A, B, 6)
  BODY_LAST(B, 7)

  // ---- Reduce-and-split butterfly: 56 shuffles total.
  const bool lo  = (lane < 32);
  const bool md  = ((lane & 16) == 0);
#define STAGE_A(e)                                                         \
  float b0_##e, b1_##e;                                                    \
  {                                                                        \
    float s0 = lo ? a2_##e : a0_##e;                                       \
    float s1 = lo ? a3_##e : a1_##e;                                       \
    const float r0 = __shfl_xor(s0, 32, 64);                               \
    const float r1 = __shfl_xor(s1, 32, 64);                               \
    b0_##e = (lo ? a0_##e : a2_##e) + r0;                                  \
    b1_##e = (lo ? a1_##e : a3_##e) + r1;                                  \
  }
  FOR_E(STAGE_A)
#define STAGE_B(e)                                                         \
  float c_##e;                                                             \
  {                                                                        \
    float s = md ? b1_##e : b0_##e;                                        \
    const float r = __shfl_xor(s, 16, 64);                                 \
    c_##e = (md ? b0_##e : b1_##e) + r;                                    \
  }
  FOR_E(STAGE_B)
#define STAGE_CF(e)                                                        \
  c_##e += __shfl_xor(c_##e, 8, 64);                                       \
  c_##e += __shfl_xor(c_##e, 4, 64);                                       \
  c_##e += __shfl_xor(c_##e, 2, 64);                                       \
  c_##e += __shfl_xor(c_##e, 1, 64);
  FOR_E(STAGE_CF)

  // Every lane in group g now holds token (t0+g)'s 8 logits in c_0..c_7.
  const int tok = t0 + (lane >> 4);
#define SIG_E(e) const float sc_##e = 1.0f / (1.0f + __expf(-c_##e));
  FOR_E(SIG_E)

  // top-2 on biased scores; strict > keeps lowest index on ties (jax top_k)
  float m1 = -1e30f, m2 = -1e30f, s1 = 0.0f, s2 = 0.0f;
  int i1 = 0, i2 = 0;
#define TOP_E(e)                                                           \
  {                                                                        \
    const float be = sc_##e + bs_##e;                                      \
    const bool g1 = be > m1;                                               \
    const bool g2 = be > m2;                                               \
    i2 = g1 ? i1 : (g2 ? e     : i2);                                      \
    m2 = g1 ? m1 : (g2 ? be    : m2);                                      \
    s2 = g1 ? s1 : (g2 ? sc_##e : s2);                                     \
    i1 = g1 ? e     : i1;                                                  \
    m1 = g1 ? be    : m1;                                                  \
    s1 = g1 ? sc_##e : s1;                                                 \
  }
  FOR_E(TOP_E)

  const float denom = s1 + s2 + 1e-20f;
  const float n1 = s1 / denom;
  const float n2 = s2 / denom;
  float ent = -(n1 * __logf(n1) + n2 * __logf(n2));
  float ent2 = ent + __shfl_xor(ent, 16, 64);
  float ent4 = ent2 + __shfl_xor(ent2, 32, 64);

  if ((lane & 15) == 0) {
    *reinterpret_cast<float2*>(out + TOP_OFF + (size_t)tok * 2) =
        make_float2(n1, n2);
    *reinterpret_cast<float2*>(out + IDX_OFF + (size_t)tok * 2) =
        make_float2((float)i1, (float)i2);
    *reinterpret_cast<float4*>(out + SC_OFF + (size_t)tok * 8) =
        make_float4(sc_0, sc_1, sc_2, sc_3);
    *reinterpret_cast<float4*>(out + SC_OFF + (size_t)tok * 8 + 4) =
        make_float4(sc_4, sc_5, sc_6, sc_7);
    atomicAdd(&sHist[i1], 1);
    atomicAdd(&sHist[i2], 1);
  }
  if (lane == 0) atomicAdd(&sEnt, ent4);

  __syncthreads();
  if (USE_WS) {
    // Plain coalesced partial stores — zero global atomics.
    if (tid < NE) ws[(size_t)blockIdx.x * WS_ROW + tid] = (float)sHist[tid];
    if (tid == NE) ws[(size_t)blockIdx.x * WS_ROW + NE] = sEnt;
  } else {
    if (tid < NE) atomicAdd(out + HIST_OFF + tid, (float)sHist[tid]);
    if (tid == 0) atomicAdd(out + ENT_OFF, sEnt * (1.0f / (float)NT));
  }
}

// ---------------------------------------------------------------------------
// Final reduction body: 512 threads, one ws row per thread (float4 loads;
// rows are 48 B so 16B-aligned); per-wave butterfly, then wave partials.
// ---------------------------------------------------------------------------
__device__ __forceinline__ void finalize_body(const float* __restrict__ ws,
                                              float* __restrict__ out) {
  __shared__ float red[8][9];
  const int tid  = threadIdx.x;
  const int wave = tid >> 6;
  const int lane = tid & 63;

  const float4* p = reinterpret_cast<const float4*>(ws + (size_t)tid * WS_ROW);
  const float4 v0 = p[0];   // h0..h3
  const float4 v1 = p[1];   // h4..h7
  const float4 v2 = p[2];   // ent, pad...
  float h0 = v0.x, h1 = v0.y, h2 = v0.z, h3 = v0.w;
  float h4 = v1.x, h5 = v1.y, h6 = v1.z, h7 = v1.w, ent = v2.x;

#define REDF(v)                                                            \
  { v += __shfl_xor(v, 32, 64); v += __shfl_xor(v, 16, 64);                \
    v += __shfl_xor(v,  8, 64); v += __shfl_xor(v,  4, 64);                \
    v += __shfl_xor(v,  2, 64); v += __shfl_xor(v,  1, 64); }
  REDF(h0) REDF(h1) REDF(h2) REDF(h3) REDF(h4) REDF(h5) REDF(h6) REDF(h7)
  REDF(ent)

  if (lane == 0) {
    red[wave][0] = h0; red[wave][1] = h1; red[wave][2] = h2; red[wave][3] = h3;
    red[wave][4] = h4; red[wave][5] = h5; red[wave][6] = h6; red[wave][7] = h7;
    red[wave][8] = ent;
  }
  __syncthreads();
  if (tid < NE + 1) {    // thread i sums slot i over the 8 waves
    float s = 0.f;
#pragma unroll
    for (int w = 0; w < 8; ++w) s += red[w][tid];
    if (tid < NE) out[HIST_OFF + tid] = s;
    else          out[ENT_OFF] = s * (1.0f / (float)NT);
  }
}

// ---- Cooperative single-kernel path: router + grid.sync + block-0 finalize.
__global__ __launch_bounds__(512, 4)
void router_coop(const float* __restrict__ x, const float* __restrict__ W,
                 const float* __restrict__ bias, float* __restrict__ out,
                 float* __restrict__ ws) {
  router_body<true>(x, W, bias, out, ws);
  __threadfence();                       // partials device-visible
  cg::this_grid().sync();
  if (blockIdx.x == 0) finalize_body(ws, out);
}

// ---- Separate-kernel fallback (round-11 structure).
__global__ __launch_bounds__(512, 4)
void router_sep(const float* __restrict__ x, const float* __restrict__ W,
                const float* __restrict__ bias, float* __restrict__ out,
                float* __restrict__ ws) {
  router_body<true>(x, W, bias, out, ws);
}

__global__ __launch_bounds__(512, 4)
void router_atomic(const float* __restrict__ x, const float* __restrict__ W,
                   const float* __restrict__ bias, float* __restrict__ out,
                   float* __restrict__ ws) {
  router_body<false>(x, W, bias, out, ws);
}

__global__ __launch_bounds__(512)
void finalize(const float* __restrict__ ws, float* __restrict__ out) {
  finalize_body(ws, out);
}

extern "C" void kernel_launch(void* const* d_in, const int* in_sizes, int n_in,
                              void* d_out, int out_size, void* d_ws, size_t ws_size,
                              hipStream_t stream) {
  (void)in_sizes; (void)n_in; (void)out_size;
  const float* x    = (const float*)d_in[0];
  const float* W    = (const float*)d_in[1];
  const float* bias = (const float*)d_in[2];
  float* out = (float*)d_out;
  float* wsf = (float*)d_ws;

  const bool use_ws = (d_ws != nullptr) &&
                      (ws_size >= (size_t)NBLK * WS_ROW * sizeof(float));
  if (use_ws) {
    void* args[] = {(void*)&x, (void*)&W, (void*)&bias, (void*)&out,
                    (void*)&wsf};
    hipError_t err = hipLaunchCooperativeKernel(
        (const void*)router_coop, dim3(NBLK), dim3(512), args, 0, stream);
    if (err == hipSuccess) return;
    // Cooperative launch unavailable -> round-11 two-kernel path.
    (void)hipGetLastError();   // clear error state
    router_sep<<<NBLK, 512, 0, stream>>>(x, W, bias, out, wsf);
    finalize<<<1, 512, 0, stream>>>(wsf, out);
  } else {
    init_tail<<<1, 64, 0, stream>>>(out);
    router_atomic<<<NBLK, 512, 0, stream>>>(x, W, bias, out, wsf);
  }
}

// Round 13
// 48.609 us; speedup vs baseline: 4.2052x; 4.2052x over previous
//
#include <hip/hip_runtime.h>
#include <math.h>

#define NT  16384
#define HID 2048
#define NE  8
#define NBLK 512   // router blocks

constexpr int TOP_OFF  = 0;                 // top_scores  (NT,2)
constexpr int SC_OFF   = NT * 2;            // scores      (NT,8)
constexpr int IDX_OFF  = SC_OFF + NT * NE;  // indices     (NT,2)
constexpr int HIST_OFF = IDX_OFF + NT * 2;  // counts      (8)
constexpr int ENT_OFF  = HIST_OFF + NE;     // entropy     (1)

// ws layout: float ws[NBLK][12] ([0..7]=hist, [8]=ent) + arrival counter.
constexpr int WS_ROW  = 12;
constexpr int CNT_OFF = NBLK * WS_ROW;      // uint32 arrival counter

typedef float f32x4 __attribute__((ext_vector_type(4)));

// Nontemporal stream load: x is read-once (128 MB) — don't allocate in L2/L3.
static __device__ __forceinline__ f32x4 ntload4(const float* p) {
  return __builtin_nontemporal_load(reinterpret_cast<const f32x4*>(p));
}

__global__ void init_tail(float* __restrict__ out) {
  const int i = threadIdx.x;
  if (i < NE + 1) out[HIST_OFF + i] = 0.0f;
}

// X-macro over experts: NAMED scalars only — no indexable per-thread arrays
// (round 1's arrays spilled ~210 MB of scratch to HBM).
#define FOR_E(F) F(0) F(1) F(2) F(3) F(4) F(5) F(6) F(7)

// Final reduction: 512 threads, one ws row per thread (float4 loads; rows
// are 48 B so 16B-aligned); per-wave butterfly, then wave partials via LDS.
__device__ __forceinline__ void finalize_body(const float* __restrict__ ws,
                                              float* __restrict__ out) {
  __shared__ float red[8][9];
  const int tid  = threadIdx.x;
  const int wave = tid >> 6;
  const int lane = tid & 63;

  const float4* p = reinterpret_cast<const float4*>(ws + (size_t)tid * WS_ROW);
  const float4 v0 = p[0];   // h0..h3
  const float4 v1 = p[1];   // h4..h7
  const float4 v2 = p[2];   // ent, pad...
  float h0 = v0.x, h1 = v0.y, h2 = v0.z, h3 = v0.w;
  float h4 = v1.x, h5 = v1.y, h6 = v1.z, h7 = v1.w, ent = v2.x;

#define REDF(v)                                                            \
  { v += __shfl_xor(v, 32, 64); v += __shfl_xor(v, 16, 64);                \
    v += __shfl_xor(v,  8, 64); v += __shfl_xor(v,  4, 64);                \
    v += __shfl_xor(v,  2, 64); v += __shfl_xor(v,  1, 64); }
  REDF(h0) REDF(h1) REDF(h2) REDF(h3) REDF(h4) REDF(h5) REDF(h6) REDF(h7)
  REDF(ent)

  if (lane == 0) {
    red[wave][0] = h0; red[wave][1] = h1; red[wave][2] = h2; red[wave][3] = h3;
    red[wave][4] = h4; red[wave][5] = h5; red[wave][6] = h6; red[wave][7] = h7;
    red[wave][8] = ent;
  }
  __syncthreads();
  if (tid < NE + 1) {    // thread i sums slot i over the 8 waves
    float s = 0.f;
#pragma unroll
    for (int w = 0; w < 8; ++w) s += red[w][tid];
    if (tid < NE) out[HIST_OFF + tid] = s;
    else          out[ENT_OFF] = s * (1.0f / (float)NT);
  }
}

// 512 threads = 8 waves/block; 64.5 KiB LDS -> 2 blocks/CU -> 16 waves/CU.
// LASTBLK: per-block partials to ws; the last-arriving block (device-scope
// atomic counter, modular — needs NO init: any 512 consecutive increments
// contain exactly one old%512==511, and 512 | 2^32) finalizes in-kernel.
template <bool LASTBLK>
__global__ __launch_bounds__(512, 4)
void router_kernel(const float* __restrict__ x, const float* __restrict__ W,
                   const float* __restrict__ bias, float* __restrict__ out,
                   float* __restrict__ ws) {
  __shared__ float sW[NE * HID];   // 64 KiB
  __shared__ int   sHist[NE];
  __shared__ float sEnt;
  __shared__ int   sLast;

  const int tid  = threadIdx.x;
  const int wave = tid >> 6;
  const int lane = tid & 63;

  // 4 tokens per wave, 32 per block, 512 blocks.
  const int t0 = blockIdx.x * 32 + wave * 4;
  const float* xb = x + (size_t)t0 * HID;
  // Column-phase rotation — ESSENTIAL (round 9 ablation: removing it cost
  // +6 µs; spreads concurrent requests across HBM channels).
  const int phase = (wave + (int)blockIdx.x) & 7;

#define OFFX(it) ((((it) + phase) & 7) * 256 + lane * 4)
#define XLOAD(N, off)                                                      \
  N##0 = ntload4(xb + (off));                                              \
  N##1 = ntload4(xb + HID + (off));                                        \
  N##2 = ntload4(xb + 2 * HID + (off));                                    \
  N##3 = ntload4(xb + 3 * HID + (off));

  f32x4 A0, A1, A2, A3, B0, B1, B2, B3;

  // ---- PEELED iter-0 x loads, issued BEFORE W staging: the x stream starts
  // flowing during the W-staging latency (round 11: −0.75 µs).
  { const int o0 = OFFX(0); XLOAD(A, o0) }

  // Stage W into LDS: 16384 floats = 4096 float4.
#if __has_builtin(__builtin_amdgcn_global_load_lds)
  // Direct global->LDS DMA, 16 B/lane: no VGPR round-trip. LDS dest rule
  // (m104): wave-uniform base + lane*16.
  {
    const float4* Wv  = reinterpret_cast<const float4*>(W);
    float4*       sWv = reinterpret_cast<float4*>(sW);
#pragma unroll
    for (int i = 0; i < 8; ++i) {
      const float4* gsrc = Wv + i * 512 + tid;        // per-lane
      float4*       ldst = sWv + i * 512 + wave * 64; // wave-uniform
      __builtin_amdgcn_global_load_lds(
          (const __attribute__((address_space(1))) void*)gsrc,
          (__attribute__((address_space(3))) void*)ldst, 16, 0, 0);
    }
  }
#else
  {
    const float4* Wv  = reinterpret_cast<const float4*>(W);
    float4*       sWv = reinterpret_cast<float4*>(sW);
#pragma unroll
    for (int i = 0; i < 8; ++i) sWv[i * 512 + tid] = Wv[i * 512 + tid];
  }
#endif
  if (tid < NE) sHist[tid] = 0;
  if (tid == 0) sEnt = 0.0f;

#define DECL_BS(e) const float bs_##e = bias[e];
  FOR_E(DECL_BS)

  __syncthreads();   // drains vmcnt(0): W in LDS and peeled A in VGPRs

#define DECL_ACC(e) float a0_##e = 0.f, a1_##e = 0.f, a2_##e = 0.f, a3_##e = 0.f;
  FOR_E(DECL_ACC)

  // NOTE: C##0.x is an invalid paste ("0.x" lexes as one pp-number), so bind
  // local copies first; compiler copy-propagates them away.
#define FMA_E(e, q0, q1, q2, q3, offc)                                     \
  {                                                                        \
    const float4 wv = *reinterpret_cast<const float4*>(sW + e * HID + (offc)); \
    a0_##e += q0.x * wv.x + q0.y * wv.y + q0.z * wv.z + q0.w * wv.w;       \
    a1_##e += q1.x * wv.x + q1.y * wv.y + q1.z * wv.z + q1.w * wv.w;       \
    a2_##e += q2.x * wv.x + q2.y * wv.y + q2.z * wv.z + q2.w * wv.w;       \
    a3_##e += q3.x * wv.x + q3.y * wv.y + q3.z * wv.z + q3.w * wv.w;       \
  }

#define FMA_ALL(q0, q1, q2, q3, offc)                                      \
    FMA_E(0, q0, q1, q2, q3, offc) FMA_E(1, q0, q1, q2, q3, offc)          \
    FMA_E(2, q0, q1, q2, q3, offc) FMA_E(3, q0, q1, q2, q3, offc)          \
    FMA_E(4, q0, q1, q2, q3, offc) FMA_E(5, q0, q1, q2, q3, offc)          \
    FMA_E(6, q0, q1, q2, q3, offc) FMA_E(7, q0, q1, q2, q3, offc)

#define BODY(C, N, itc)                                                    \
  {                                                                        \
    const int offn = OFFX(itc + 1);                                        \
    XLOAD(N, offn)                                                         \
    const f32x4 q0 = C##0 , q1 = C##1 , q2 = C##2 , q3 = C##3 ;            \
    const int offc = OFFX(itc);                                            \
    FMA_ALL(q0, q1, q2, q3, offc)                                          \
  }
#define BODY_LAST(C, itc)                                                  \
  {                                                                        \
    const f32x4 q0 = C##0 , q1 = C##1 , q2 = C##2 , q3 = C##3 ;            \
    const int offc = OFFX(itc);                                            \
    FMA_ALL(q0, q1, q2, q3, offc)                                          \
  }

  BODY(A, B, 0)
  BODY(B, A, 1)
  BODY(A, B, 2)
  BODY(B, A, 3)
  BODY(A, B, 4)
  BODY(B, A, 5)
  BODY(A, B, 6)
  BODY_LAST(B, 7)

  // ---- Reduce-and-split butterfly: 56 shuffles total.
  const bool lo  = (lane < 32);
  const bool md  = ((lane & 16) == 0);
#define STAGE_A(e)                                                         \
  float b0_##e, b1_##e;                                                    \
  {                                                                        \
    float s0 = lo ? a2_##e : a0_##e;                                       \
    float s1 = lo ? a3_##e : a1_##e;                                       \
    const float r0 = __shfl_xor(s0, 32, 64);                               \
    const float r1 = __shfl_xor(s1, 32, 64);                               \
    b0_##e = (lo ? a0_##e : a2_##e) + r0;                                  \
    b1_##e = (lo ? a1_##e : a3_##e) + r1;                                  \
  }
  FOR_E(STAGE_A)
#define STAGE_B(e)                                                         \
  float c_##e;                                                             \
  {                                                                        \
    float s = md ? b1_##e : b0_##e;                                        \
    const float r = __shfl_xor(s, 16, 64);                                 \
    c_##e = (md ? b0_##e : b1_##e) + r;                                    \
  }
  FOR_E(STAGE_B)
#define STAGE_CF(e)                                                        \
  c_##e += __shfl_xor(c_##e, 8, 64);                                       \
  c_##e += __shfl_xor(c_##e, 4, 64);                                       \
  c_##e += __shfl_xor(c_##e, 2, 64);                                       \
  c_##e += __shfl_xor(c_##e, 1, 64);
  FOR_E(STAGE_CF)

  // Every lane in group g now holds token (t0+g)'s 8 logits in c_0..c_7.
  const int tok = t0 + (lane >> 4);
#define SIG_E(e) const float sc_##e = 1.0f / (1.0f + __expf(-c_##e));
  FOR_E(SIG_E)

  // top-2 on biased scores; strict > keeps lowest index on ties (jax top_k)
  float m1 = -1e30f, m2 = -1e30f, s1 = 0.0f, s2 = 0.0f;
  int i1 = 0, i2 = 0;
#define TOP_E(e)                                                           \
  {                                                                        \
    const float be = sc_##e + bs_##e;                                      \
    const bool g1 = be > m1;                                               \
    const bool g2 = be > m2;                                               \
    i2 = g1 ? i1 : (g2 ? e     : i2);                                      \
    m2 = g1 ? m1 : (g2 ? be    : m2);                                      \
    s2 = g1 ? s1 : (g2 ? sc_##e : s2);                                     \
    i1 = g1 ? e     : i1;                                                  \
    m1 = g1 ? be    : m1;                                                  \
    s1 = g1 ? sc_##e : s1;                                                 \
  }
  FOR_E(TOP_E)

  const float denom = s1 + s2 + 1e-20f;
  const float n1 = s1 / denom;
  const float n2 = s2 / denom;
  float ent = -(n1 * __logf(n1) + n2 * __logf(n2));
  float ent2 = ent + __shfl_xor(ent, 16, 64);
  float ent4 = ent2 + __shfl_xor(ent2, 32, 64);

  if ((lane & 15) == 0) {
    *reinterpret_cast<float2*>(out + TOP_OFF + (size_t)tok * 2) =
        make_float2(n1, n2);
    *reinterpret_cast<float2*>(out + IDX_OFF + (size_t)tok * 2) =
        make_float2((float)i1, (float)i2);
    *reinterpret_cast<float4*>(out + SC_OFF + (size_t)tok * 8) =
        make_float4(sc_0, sc_1, sc_2, sc_3);
    *reinterpret_cast<float4*>(out + SC_OFF + (size_t)tok * 8 + 4) =
        make_float4(sc_4, sc_5, sc_6, sc_7);
    atomicAdd(&sHist[i1], 1);
    atomicAdd(&sHist[i2], 1);
  }
  if (lane == 0) atomicAdd(&sEnt, ent4);

  __syncthreads();
  if (LASTBLK) {
    // Per-block partials, plain coalesced stores.
    if (tid < NE) ws[(size_t)blockIdx.x * WS_ROW + tid] = (float)sHist[tid];
    if (tid == NE) ws[(size_t)blockIdx.x * WS_ROW + NE] = sEnt;
    __syncthreads();                     // partial stores issued block-wide
    if (tid == 0) {
      __threadfence();                   // release: L2 writeback to LLC
      const unsigned old =
          atomicAdd(reinterpret_cast<unsigned*>(ws + CNT_OFF), 1u);
      sLast = ((old & (NBLK - 1)) == (NBLK - 1)) ? 1 : 0;
    }
    __syncthreads();
    if (sLast) {
      __threadfence();                   // acquire: invalidate stale L2
      finalize_body(ws, out);
    }
  } else {
    if (tid < NE) atomicAdd(out + HIST_OFF + tid, (float)sHist[tid]);
    if (tid == 0) atomicAdd(out + ENT_OFF, sEnt * (1.0f / (float)NT));
  }
}

extern "C" void kernel_launch(void* const* d_in, const int* in_sizes, int n_in,
                              void* d_out, int out_size, void* d_ws, size_t ws_size,
                              hipStream_t stream) {
  (void)in_sizes; (void)n_in; (void)out_size;
  const float* x    = (const float*)d_in[0];
  const float* W    = (const float*)d_in[1];
  const float* bias = (const float*)d_in[2];
  float* out = (float*)d_out;
  float* wsf = (float*)d_ws;

  const bool use_ws = (d_ws != nullptr) &&
                      (ws_size >= (size_t)(CNT_OFF + 4) * sizeof(float));
  if (use_ws) {
    // Single dispatch: router + last-block in-kernel finalize.
    router_kernel<true><<<NBLK, 512, 0, stream>>>(x, W, bias, out, wsf);
  } else {
    init_tail<<<1, 64, 0, stream>>>(out);
    router_kernel<false><<<NBLK, 512, 0, stream>>>(x, W, bias, out, wsf);
  }
}

// Round 14
// 30.178 us; speedup vs baseline: 6.7736x; 1.6108x over previous
//
#include <hip/hip_runtime.h>
#include <math.h>

#define NT  16384
#define HID 2048
#define NE  8
#define NBLK 512   // router blocks

constexpr int TOP_OFF  = 0;                 // top_scores  (NT,2)
constexpr int SC_OFF   = NT * 2;            // scores      (NT,8)
constexpr int IDX_OFF  = SC_OFF + NT * NE;  // indices     (NT,2)
constexpr int HIST_OFF = IDX_OFF + NT * 2;  // counts      (8)
constexpr int ENT_OFF  = HIST_OFF + NE;     // entropy     (1)

// ws layout: float ws[NBLK][12] — [0..7]=hist, [8]=ent, [9..11]=pad
constexpr int WS_ROW = 12;

typedef float f32x4 __attribute__((ext_vector_type(4)));

// Nontemporal stream load: x is read-once (128 MB) — don't allocate in L2/L3.
static __device__ __forceinline__ f32x4 ntload4(const float* p) {
  return __builtin_nontemporal_load(reinterpret_cast<const f32x4*>(p));
}

__global__ void init_tail(float* __restrict__ out) {
  const int i = threadIdx.x;
  if (i < NE + 1) out[HIST_OFF + i] = 0.0f;
}

// X-macro over experts: NAMED scalars only — no indexable per-thread arrays
// (round 1's arrays spilled ~210 MB of scratch to HBM).
#define FOR_E(F) F(0) F(1) F(2) F(3) F(4) F(5) F(6) F(7)

// 512 threads = 8 waves/block; 64.5 KiB LDS -> 2 blocks/CU -> 16 waves/CU.
template <bool USE_WS>
__global__ __launch_bounds__(512, 4)
void router_kernel(const float* __restrict__ x, const float* __restrict__ W,
                   const float* __restrict__ bias, float* __restrict__ out,
                   float* __restrict__ ws) {
  __shared__ float sW[NE * HID];   // 64 KiB
  __shared__ int   sHist[NE];
  __shared__ float sEnt;

  const int tid  = threadIdx.x;
  const int wave = tid >> 6;
  const int lane = tid & 63;

  // 4 tokens per wave, 32 per block, 512 blocks.
  const int t0 = blockIdx.x * 32 + wave * 4;
  const float* xb = x + (size_t)t0 * HID;
  // Column-phase rotation — ESSENTIAL (round 9 ablation: removing it cost
  // +6 µs; spreads concurrent requests across HBM channels).
  const int phase = (wave + (int)blockIdx.x) & 7;

#define OFFX(it) ((((it) + phase) & 7) * 256 + lane * 4)
#define XLOAD(N, off)                                                      \
  N##0 = ntload4(xb + (off));                                              \
  N##1 = ntload4(xb + HID + (off));                                        \
  N##2 = ntload4(xb + 2 * HID + (off));                                    \
  N##3 = ntload4(xb + 3 * HID + (off));

  f32x4 A0, A1, A2, A3, B0, B1, B2, B3;

  // ---- PEELED iter-0 x loads, issued BEFORE W staging: the x stream starts
  // flowing during the W-staging latency (round 11: −0.75 µs).
  { const int o0 = OFFX(0); XLOAD(A, o0) }

  // Stage W into LDS: 16384 floats = 4096 float4.
#if __has_builtin(__builtin_amdgcn_global_load_lds)
  // Direct global->LDS DMA, 16 B/lane: no VGPR round-trip. LDS dest rule
  // (m104): wave-uniform base + lane*16.
  {
    const float4* Wv  = reinterpret_cast<const float4*>(W);
    float4*       sWv = reinterpret_cast<float4*>(sW);
#pragma unroll
    for (int i = 0; i < 8; ++i) {
      const float4* gsrc = Wv + i * 512 + tid;        // per-lane
      float4*       ldst = sWv + i * 512 + wave * 64; // wave-uniform
      __builtin_amdgcn_global_load_lds(
          (const __attribute__((address_space(1))) void*)gsrc,
          (__attribute__((address_space(3))) void*)ldst, 16, 0, 0);
    }
  }
#else
  {
    const float4* Wv  = reinterpret_cast<const float4*>(W);
    float4*       sWv = reinterpret_cast<float4*>(sW);
#pragma unroll
    for (int i = 0; i < 8; ++i) sWv[i * 512 + tid] = Wv[i * 512 + tid];
  }
#endif
  if (tid < NE) sHist[tid] = 0;
  if (tid == 0) sEnt = 0.0f;

#define DECL_BS(e) const float bs_##e = bias[e];
  FOR_E(DECL_BS)

  __syncthreads();   // drains vmcnt(0): W in LDS and peeled A in VGPRs

#define DECL_ACC(e) float a0_##e = 0.f, a1_##e = 0.f, a2_##e = 0.f, a3_##e = 0.f;
  FOR_E(DECL_ACC)

  // NOTE: C##0.x is an invalid paste ("0.x" lexes as one pp-number), so bind
  // local copies first; compiler copy-propagates them away.
#define FMA_E(e, q0, q1, q2, q3, offc)                                     \
  {                                                                        \
    const float4 wv = *reinterpret_cast<const float4*>(sW + e * HID + (offc)); \
    a0_##e += q0.x * wv.x + q0.y * wv.y + q0.z * wv.z + q0.w * wv.w;       \
    a1_##e += q1.x * wv.x + q1.y * wv.y + q1.z * wv.z + q1.w * wv.w;       \
    a2_##e += q2.x * wv.x + q2.y * wv.y + q2.z * wv.z + q2.w * wv.w;       \
    a3_##e += q3.x * wv.x + q3.y * wv.y + q3.z * wv.z + q3.w * wv.w;       \
  }

#define FMA_ALL(q0, q1, q2, q3, offc)                                      \
    FMA_E(0, q0, q1, q2, q3, offc) FMA_E(1, q0, q1, q2, q3, offc)          \
    FMA_E(2, q0, q1, q2, q3, offc) FMA_E(3, q0, q1, q2, q3, offc)          \
    FMA_E(4, q0, q1, q2, q3, offc) FMA_E(5, q0, q1, q2, q3, offc)          \
    FMA_E(6, q0, q1, q2, q3, offc) FMA_E(7, q0, q1, q2, q3, offc)

#define BODY(C, N, itc)                                                    \
  {                                                                        \
    const int offn = OFFX(itc + 1);                                        \
    XLOAD(N, offn)                                                         \
    const f32x4 q0 = C##0 , q1 = C##1 , q2 = C##2 , q3 = C##3 ;            \
    const int offc = OFFX(itc);                                            \
    FMA_ALL(q0, q1, q2, q3, offc)                                          \
  }
#define BODY_LAST(C, itc)                                                  \
  {                                                                        \
    const f32x4 q0 = C##0 , q1 = C##1 , q2 = C##2 , q3 = C##3 ;            \
    const int offc = OFFX(itc);                                            \
    FMA_ALL(q0, q1, q2, q3, offc)                                          \
  }

  BODY(A, B, 0)
  BODY(B, A, 1)
  BODY(A, B, 2)
  BODY(B, A, 3)
  BODY(A, B, 4)
  BODY(B, A, 5)
  BODY(A, B, 6)
  BODY_LAST(B, 7)

  // ---- Reduce-and-split butterfly: 56 shuffles total.
  const bool lo  = (lane < 32);
  const bool md  = ((lane & 16) == 0);
#define STAGE_A(e)                                                         \
  float b0_##e, b1_##e;                                                    \
  {                                                                        \
    float s0 = lo ? a2_##e : a0_##e;                                       \
    float s1 = lo ? a3_##e : a1_##e;                                       \
    const float r0 = __shfl_xor(s0, 32, 64);                               \
    const float r1 = __shfl_xor(s1, 32, 64);                               \
    b0_##e = (lo ? a0_##e : a2_##e) + r0;                                  \
    b1_##e = (lo ? a1_##e : a3_##e) + r1;                                  \
  }
  FOR_E(STAGE_A)
#define STAGE_B(e)                                                         \
  float c_##e;                                                             \
  {                                                                        \
    float s = md ? b1_##e : b0_##e;                                        \
    const float r = __shfl_xor(s, 16, 64);                                 \
    c_##e = (md ? b0_##e : b1_##e) + r;                                    \
  }
  FOR_E(STAGE_B)
#define STAGE_CF(e)                                                        \
  c_##e += __shfl_xor(c_##e, 8, 64);                                       \
  c_##e += __shfl_xor(c_##e, 4, 64);                                       \
  c_##e += __shfl_xor(c_##e, 2, 64);                                       \
  c_##e += __shfl_xor(c_##e, 1, 64);
  FOR_E(STAGE_CF)

  // Every lane in group g now holds token (t0+g)'s 8 logits in c_0..c_7.
  const int tok = t0 + (lane >> 4);
#define SIG_E(e) const float sc_##e = 1.0f / (1.0f + __expf(-c_##e));
  FOR_E(SIG_E)

  // top-2 on biased scores; strict > keeps lowest index on ties (jax top_k)
  float m1 = -1e30f, m2 = -1e30f, s1 = 0.0f, s2 = 0.0f;
  int i1 = 0, i2 = 0;
#define TOP_E(e)                                                           \
  {                                                                        \
    const float be = sc_##e + bs_##e;                                      \
    const bool g1 = be > m1;                                               \
    const bool g2 = be > m2;                                               \
    i2 = g1 ? i1 : (g2 ? e     : i2);                                      \
    m2 = g1 ? m1 : (g2 ? be    : m2);                                      \
    s2 = g1 ? s1 : (g2 ? sc_##e : s2);                                     \
    i1 = g1 ? e     : i1;                                                  \
    m1 = g1 ? be    : m1;                                                  \
    s1 = g1 ? sc_##e : s1;                                                 \
  }
  FOR_E(TOP_E)

  const float denom = s1 + s2 + 1e-20f;
  const float n1 = s1 / denom;
  const float n2 = s2 / denom;
  float ent = -(n1 * __logf(n1) + n2 * __logf(n2));
  // Wave entropy: all lanes in a group hold the group's ent; 2 shuffles sum
  // the 4 groups.
  float ent2 = ent + __shfl_xor(ent, 16, 64);
  float ent4 = ent2 + __shfl_xor(ent2, 32, 64);

  if ((lane & 15) == 0) {
    *reinterpret_cast<float2*>(out + TOP_OFF + (size_t)tok * 2) =
        make_float2(n1, n2);
    *reinterpret_cast<float2*>(out + IDX_OFF + (size_t)tok * 2) =
        make_float2((float)i1, (float)i2);
    *reinterpret_cast<float4*>(out + SC_OFF + (size_t)tok * 8) =
        make_float4(sc_0, sc_1, sc_2, sc_3);
    *reinterpret_cast<float4*>(out + SC_OFF + (size_t)tok * 8 + 4) =
        make_float4(sc_4, sc_5, sc_6, sc_7);
    atomicAdd(&sHist[i1], 1);
    atomicAdd(&sHist[i2], 1);
  }
  if (lane == 0) atomicAdd(&sEnt, ent4);

  __syncthreads();
  if (USE_WS) {
    // Plain coalesced partial stores — zero global atomics.
    if (tid < NE) ws[(size_t)blockIdx.x * WS_ROW + tid] = (float)sHist[tid];
    if (tid == NE) ws[(size_t)blockIdx.x * WS_ROW + NE] = sEnt;
  } else {
    if (tid < NE) atomicAdd(out + HIST_OFF + tid, (float)sHist[tid]);
    if (tid == 0) atomicAdd(out + ENT_OFF, sEnt * (1.0f / (float)NT));
  }
}

// 512 threads: one ws row per thread (float4 row loads; rows are 48 B so
// 16B-aligned); per-wave butterfly, then wave partials via LDS.
__global__ __launch_bounds__(512)
void finalize(const float* __restrict__ ws, float* __restrict__ out) {
  __shared__ float red[8][9];
  const int tid  = threadIdx.x;
  const int wave = tid >> 6;
  const int lane = tid & 63;

  const float4* p = reinterpret_cast<const float4*>(ws + (size_t)tid * WS_ROW);
  const float4 v0 = p[0];   // h0..h3
  const float4 v1 = p[1];   // h4..h7
  const float4 v2 = p[2];   // ent, pad...
  float h0 = v0.x, h1 = v0.y, h2 = v0.z, h3 = v0.w;
  float h4 = v1.x, h5 = v1.y, h6 = v1.z, h7 = v1.w, ent = v2.x;

#define REDF(v)                                                            \
  { v += __shfl_xor(v, 32, 64); v += __shfl_xor(v, 16, 64);                \
    v += __shfl_xor(v,  8, 64); v += __shfl_xor(v,  4, 64);                \
    v += __shfl_xor(v,  2, 64); v += __shfl_xor(v,  1, 64); }
  REDF(h0) REDF(h1) REDF(h2) REDF(h3) REDF(h4) REDF(h5) REDF(h6) REDF(h7)
  REDF(ent)

  if (lane == 0) {
    red[wave][0] = h0; red[wave][1] = h1; red[wave][2] = h2; red[wave][3] = h3;
    red[wave][4] = h4; red[wave][5] = h5; red[wave][6] = h6; red[wave][7] = h7;
    red[wave][8] = ent;
  }
  __syncthreads();
  if (tid < NE + 1) {    // thread i sums slot i over the 8 waves
    float s = 0.f;
#pragma unroll
    for (int w = 0; w < 8; ++w) s += red[w][tid];
    if (tid < NE) out[HIST_OFF + tid] = s;
    else          out[ENT_OFF] = s * (1.0f / (float)NT);
  }
}

extern "C" void kernel_launch(void* const* d_in, const int* in_sizes, int n_in,
                              void* d_out, int out_size, void* d_ws, size_t ws_size,
                              hipStream_t stream) {
  (void)in_sizes; (void)n_in; (void)out_size;
  const float* x    = (const float*)d_in[0];
  const float* W    = (const float*)d_in[1];
  const float* bias = (const float*)d_in[2];
  float* out = (float*)d_out;

  const bool use_ws = (d_ws != nullptr) &&
                      (ws_size >= (size_t)NBLK * WS_ROW * sizeof(float));
  if (use_ws) {
    router_kernel<true><<<NBLK, 512, 0, stream>>>(x, W, bias, out, (float*)d_ws);
    finalize<<<1, 512, 0, stream>>>((const float*)d_ws, out);
  } else {
    init_tail<<<1, 64, 0, stream>>>(out);
    router_kernel<false><<<NBLK, 512, 0, stream>>>(x, W, bias, out, (float*)d_ws);
  }
}